// Round 14
// baseline (736.818 us; speedup 1.0000x reference)
//
#include <hip/hip_runtime.h>
#include <hip/hip_bf16.h>
#include <stdint.h>

#define TOK 4096
#define SEQ 2048
#define DM 2048
#define NH 16
#define NKV 4
#define HDIM 128
#define HID 8192
#define WIN 1024
#define SINKN 4

typedef float f32x4 __attribute__((ext_vector_type(4)));
typedef __bf16 bf16x8 __attribute__((ext_vector_type(8)));
typedef unsigned short u16;
typedef unsigned int u32;

#define VM(n) asm volatile("s_waitcnt vmcnt(" #n ")" ::: "memory")
#define LG(n) asm volatile("s_waitcnt lgkmcnt(" #n ")" ::: "memory")
#define SCHED0 __builtin_amdgcn_sched_barrier(0)

__device__ __forceinline__ u16 f2bf(float f) {
  union { float f; u32 u; } v; v.f = f;
  return (u16)((v.u + 0x7fffu + ((v.u >> 16) & 1u)) >> 16);
}
__device__ __forceinline__ float bf2f(u16 h) {
  union { u32 u; float f; } v; v.u = ((u32)h) << 16;
  return v.f;
}
__device__ __forceinline__ f32x4 mfma16(bf16x8 a, bf16x8 b, f32x4 c) {
  return __builtin_amdgcn_mfma_f32_16x16x32_bf16(a, b, c, 0, 0, 0);
}
__device__ __forceinline__ void gld16(const u16* g, u16* l) {
  __builtin_amdgcn_global_load_lds(
      (const __attribute__((address_space(1))) u32*)g,
      (__attribute__((address_space(3))) u32*)l, 16, 0, 0);
}
__device__ __forceinline__ void bar() {
  asm volatile("s_barrier" ::: "memory");
}
// Inverse swizzle for 64B-row tiles ([rows][32] u16) used by attn staging.
__device__ __forceinline__ void swz_rc(int c, int& row, int& k8) {
  row = 2 * (c >> 3) + (((c >> 2) & 1) ^ ((c >> 4) & 1));
  k8 = (c & 3) ^ (row & 3);
}
// XCD-chunked + grouped raster (G=8).
__device__ __forceinline__ void raster8(int wg, int nwg, int nbx, int& bx, int& by) {
  int cpx = nwg >> 3;
  int s = (wg & 7) * cpx + (wg >> 3);
  by = 8 * (s / (8 * nbx)) + (s & 7);
  bx = (s >> 3) % nbx;
}

// -------- merged weight transpose fp32[K][N] -> bf16[N][K], 7 segments ------
__global__ __launch_bounds__(256)
void wtrans_all(const float* __restrict__ wq, const float* __restrict__ wk,
                const float* __restrict__ wv, const float* __restrict__ wo,
                const float* __restrict__ wg, const float* __restrict__ wu,
                const float* __restrict__ wd,
                u16* __restrict__ dqkv, u16* __restrict__ dwo,
                u16* __restrict__ dwg, u16* __restrict__ dwu,
                u16* __restrict__ dwd)
{
  int id = blockIdx.x;
  const float* src; u16* dst; int K, N, lgn;
  if (id < 4096)       { src = wq; dst = dqkv;                        K = 2048; N = 2048; lgn = 6; }
  else if (id < 5120)  { id -= 4096;  src = wk; dst = dqkv + (size_t)DM * DM;          K = 2048; N = 512;  lgn = 4; }
  else if (id < 6144)  { id -= 5120;  src = wv; dst = dqkv + (size_t)(DM + 512) * DM;  K = 2048; N = 512;  lgn = 4; }
  else if (id < 10240) { id -= 6144;  src = wo; dst = dwo;            K = 2048; N = 2048; lgn = 6; }
  else if (id < 26624) { id -= 10240; src = wg; dst = dwg;            K = 2048; N = 8192; lgn = 8; }
  else if (id < 43008) { id -= 26624; src = wu; dst = dwu;            K = 2048; N = 8192; lgn = 8; }
  else                 { id -= 43008; src = wd; dst = dwd;            K = 8192; N = 2048; lgn = 6; }
  int bx = id & ((1 << lgn) - 1);
  int by = id >> lgn;

  __shared__ float t[32][33];
  int tx = threadIdx.x & 31, ty = threadIdx.x >> 5;
  #pragma unroll
  for (int i = 0; i < 4; i++) {
    int r = ty + i * 8;
    t[r][tx] = src[(size_t)(by * 32 + r) * N + bx * 32 + tx];
  }
  __syncthreads();
  #pragma unroll
  for (int i = 0; i < 4; i++) {
    int r = ty + i * 8;
    dst[(size_t)(bx * 32 + r) * K + by * 32 + tx] = f2bf(t[tx][r]);
  }
}

// ---- V transpose: bf16 [4096][ld] cols -> [(b*4+hk)*128+d][2048] -----------
__global__ __launch_bounds__(256)
void vtrans(const u16* __restrict__ in, int ld, u16* __restrict__ out)
{
  __shared__ u16 t[32][33];
  int tx = threadIdx.x & 31, ty = threadIdx.x >> 5;
  int bx = blockIdx.x;
  int by = blockIdx.y;
  #pragma unroll
  for (int i = 0; i < 4; i++) {
    int r = ty + i * 8;
    t[r][tx] = in[(size_t)(by * 32 + r) * ld + bx * 32 + tx];
  }
  __syncthreads();
  int b = (by * 32) >> 11;
  int s0 = (by * 32) & (SEQ - 1);
  #pragma unroll
  for (int i = 0; i < 4; i++) {
    int c = bx * 32 + ty + i * 8;
    out[(size_t)(b * (NKV * HDIM) + c) * SEQ + s0 + tx] = t[tx][ty + i * 8];
  }
}

// ---------------------------- RoPE table -----------------------------------
__global__ __launch_bounds__(256)
void rope_table_k(float* __restrict__ ct, float* __restrict__ st)
{
  int idx = blockIdx.x * 256 + threadIdx.x;
  int pos = idx >> 6, d = idx & 63;
  float inv = powf(10000.0f, -(float)d / 64.0f);
  float a = (float)pos * inv;
  ct[idx] = cosf(a);
  st[idx] = sinf(a);
}

// ----------------------- RoPE apply (in place, bf16) ------------------------
__global__ void rope_apply_k(u16* __restrict__ q, int ld,
                             const float* __restrict__ ct,
                             const float* __restrict__ st, float scale)
{
  int t = blockIdx.x;
  int hh = threadIdx.x >> 6;
  int d = threadIdx.x & 63;
  int pos = t & (SEQ - 1);
  size_t base = (size_t)t * ld + hh * HDIM + d;
  float x1 = bf2f(q[base]), x2 = bf2f(q[base + 64]);
  float c = ct[pos * 64 + d], s = st[pos * 64 + d];
  q[base]      = f2bf((x1 * c - x2 * s) * scale);
  q[base + 64] = f2bf((x2 * c + x1 * s) * scale);
}

// ------------------------------ RMSNorm ------------------------------------
__global__ __launch_bounds__(256)
void rmsnorm_k(const float* __restrict__ x, const float* __restrict__ g,
               u16* __restrict__ o)
{
  int row = blockIdx.x;
  int tid = threadIdx.x;
  const float* xr = x + (size_t)row * DM;
  float4 v0 = *(const float4*)(xr + tid * 8);
  float4 v1 = *(const float4*)(xr + tid * 8 + 4);
  float ss = v0.x*v0.x + v0.y*v0.y + v0.z*v0.z + v0.w*v0.w
           + v1.x*v1.x + v1.y*v1.y + v1.z*v1.z + v1.w*v1.w;
  #pragma unroll
  for (int d = 1; d < 64; d <<= 1) ss += __shfl_xor(ss, d);
  __shared__ float red[4];
  if ((tid & 63) == 0) red[tid >> 6] = ss;
  __syncthreads();
  float inv = rsqrtf((red[0] + red[1] + red[2] + red[3]) * (1.0f / DM) + 1e-6f);
  float4 g0 = *(const float4*)(g + tid * 8);
  float4 g1 = *(const float4*)(g + tid * 8 + 4);
  ushort4 o0, o1;
  o0.x = f2bf(v0.x * inv * g0.x); o0.y = f2bf(v0.y * inv * g0.y);
  o0.z = f2bf(v0.z * inv * g0.z); o0.w = f2bf(v0.w * inv * g0.w);
  o1.x = f2bf(v1.x * inv * g1.x); o1.y = f2bf(v1.y * inv * g1.y);
  o1.z = f2bf(v1.z * inv * g1.z); o1.w = f2bf(v1.w * inv * g1.w);
  *(ushort4*)(o + (size_t)row * DM + tid * 8) = o0;
  *(ushort4*)(o + (size_t)row * DM + tid * 8 + 4) = o1;
}

// ------------- deep-pipelined GEMM: 128 x 256, BK=64, 3-slot ring -----------
// (wo path: EPI=1 -> Cf = X + acc, no atomics)
template<int EPI>
__global__ __launch_bounds__(512, 1)
void gemmp(const u16* __restrict__ A, const u16* __restrict__ Bt,
           u16* __restrict__ Cb, float* __restrict__ Cf,
           const float* __restrict__ X, int M, int N, int K, int nbx)
{
  constexpr int ASZ = 128 * 64;
  constexpr int SLOT = ASZ + 256 * 64;
  __shared__ u16 lds[3 * SLOT];

  int bx, by;
  raster8(blockIdx.x, gridDim.x, nbx, bx, by);
  int m0 = by * 128;
  int n0 = bx * 256;

  int tid = threadIdx.x;
  int l = tid & 63, w = tid >> 6;
  int l16 = l & 15, lg = l >> 4;
  int wr = w >> 2, wc = w & 3;

  int aoff[4][2], boff[4][2];
  #pragma unroll
  for (int m = 0; m < 4; m++)
    #pragma unroll
    for (int kk = 0; kk < 2; kk++) {
      int row = wr * 64 + m * 16 + l16;
      aoff[m][kk] = ((row * 128 + kk * 64 + lg * 16) ^ ((row & 7) << 4)) >> 1;
    }
  #pragma unroll
  for (int n = 0; n < 4; n++)
    #pragma unroll
    for (int kk = 0; kk < 2; kk++) {
      int br = wc * 64 + n * 16 + l16;
      boff[n][kk] = ASZ + (((br * 128 + kk * 64 + lg * 16) ^ ((br & 7) << 4)) >> 1);
    }

  int urow = tid >> 3;
  int cc = (tid & 7) ^ (urow & 7);
  const u16* pA[2];
  const u16* pB[4];
  pA[0] = A + (size_t)(m0 + urow) * K + cc * 8;
  pA[1] = A + (size_t)(m0 + 64 + urow) * K + cc * 8;
  #pragma unroll
  for (int u = 0; u < 4; u++)
    pB[u] = Bt + (size_t)(n0 + u * 64 + urow) * K + cc * 8;

  const int NT = K >> 6;

  auto stA = [&](int tt, int u) {
    gld16(pA[u] + (size_t)tt * 64, lds + (tt % 3) * SLOT + u * 4096 + tid * 8);
  };
  auto stB = [&](int tt, int u) {
    gld16(pB[u] + (size_t)tt * 64, lds + (tt % 3) * SLOT + ASZ + u * 4096 + tid * 8);
  };

  #pragma unroll
  for (int u = 0; u < 4; u++) stB(0, u);
  stA(0, 0); stA(0, 1);
  #pragma unroll
  for (int u = 0; u < 4; u++) stB(1, u);
  stA(1, 0); stA(1, 1);
  VM(6);
  bar();

  f32x4 acc[4][4];
  f32x4 zero = {0.f, 0.f, 0.f, 0.f};
  #pragma unroll
  for (int m = 0; m < 4; m++)
    #pragma unroll
    for (int n = 0; n < 4; n++) acc[m][n] = zero;

  for (int t = 0; t < NT; ++t) {
    u16* cur = lds + (t % 3) * SLOT;
    const bool st = (t + 2 < NT);

    if (st) { stB(t + 2, 0); stB(t + 2, 1); stB(t + 2, 2); }
    bf16x8 a[4][2], b[2][2], c2[2][2];
    #pragma unroll
    for (int m = 0; m < 4; m++) {
      a[m][0] = *(const bf16x8*)(cur + aoff[m][0]);
      a[m][1] = *(const bf16x8*)(cur + aoff[m][1]);
    }
    #pragma unroll
    for (int n = 0; n < 2; n++) {
      b[n][0] = *(const bf16x8*)(cur + boff[n][0]);
      b[n][1] = *(const bf16x8*)(cur + boff[n][1]);
    }
    SCHED0;
    #pragma unroll
    for (int n = 0; n < 2; n++) {
      c2[n][0] = *(const bf16x8*)(cur + boff[n + 2][0]);
      c2[n][1] = *(const bf16x8*)(cur + boff[n + 2][1]);
    }
    bar();
    LG(4);
    SCHED0;
    __builtin_amdgcn_s_setprio(1);
    #pragma unroll
    for (int m = 0; m < 4; m++)
      #pragma unroll
      for (int n = 0; n < 2; n++) {
        acc[m][n] = mfma16(a[m][0], b[n][0], acc[m][n]);
        acc[m][n] = mfma16(a[m][1], b[n][1], acc[m][n]);
      }
    __builtin_amdgcn_s_setprio(0);
    SCHED0;
    bar();

    if (st) { stB(t + 2, 3); stA(t + 2, 0); stA(t + 2, 1); }
    if (st) { VM(6); }
    else if (t + 1 < NT) { VM(0); }
    bar();
    LG(0);
    SCHED0;
    __builtin_amdgcn_s_setprio(1);
    #pragma unroll
    for (int m = 0; m < 4; m++)
      #pragma unroll
      for (int n = 0; n < 2; n++) {
        acc[m][n + 2] = mfma16(a[m][0], c2[n][0], acc[m][n + 2]);
        acc[m][n + 2] = mfma16(a[m][1], c2[n][1], acc[m][n + 2]);
      }
    __builtin_amdgcn_s_setprio(0);
    SCHED0;
    bar();
  }

  #pragma unroll
  for (int m = 0; m < 4; m++) {
    int row = m0 + wr * 64 + m * 16 + lg * 4;
    #pragma unroll
    for (int n = 0; n < 4; n++) {
      int col = n0 + wc * 64 + n * 16 + l16;
      #pragma unroll
      for (int r = 0; r < 4; r++) {
        size_t idx = (size_t)(row + r) * N + col;
        float v = acc[m][n][r];
        if (EPI == 0) {
          Cb[idx] = f2bf(v);
        } else if (EPI == 1) {
          Cf[idx] = X[idx] + v;
        } else {
          Cf[idx] += v;
        }
      }
    }
  }
}

// ---- 256x256 GEMM, m201 schedule: BK=64, 2-slot, 4 phases/K-tile -----------
// EPI: 0 bf16 store, 4 atomicAdd fp32 (split-K). GU=1: B = gate|up, silu.
template<int EPI, int GU, int SPLITK>
__global__ __launch_bounds__(512, 1)
void gemm256(const u16* __restrict__ A, const u16* __restrict__ B1,
             const u16* __restrict__ B2, u16* __restrict__ Cb,
             float* __restrict__ Cf, int Kst, int NT, int N, int nbx)
{
  constexpr int SLOT = 32768;          // u16: A-h0|A-h1|B-h0|B-h1, 8192 each
  __shared__ u16 lds[2 * SLOT];        // 128 KiB

  int wg = blockIdx.x;
  int nwg = gridDim.x;
  int kh = 0;
  if (SPLITK) { int half = nwg >> 1; kh = (wg >= half); wg -= kh * half; nwg = half; }
  int bx, by;
  raster8(wg, nwg, nbx, bx, by);
  int m0 = by * 256;
  int n0 = bx * (GU ? 128 : 256);
  size_t k0 = (size_t)kh * NT * 64;

  int tid = threadIdx.x;
  int l = tid & 63, w = tid >> 6;
  int l16 = l & 15, lg = l >> 4;
  int wr = w >> 2, wc = w & 3;

  int aoff[4][2], boff[2][2];
  #pragma unroll
  for (int mm = 0; mm < 4; mm++)
    #pragma unroll
    for (int kk = 0; kk < 2; kk++) {
      int ar = wr * 64 + mm * 16 + l16;
      aoff[mm][kk] = ((ar * 128 + ((kk * 64 + lg * 16) ^ ((ar & 7) << 4))) >> 1);
    }
  #pragma unroll
  for (int nn = 0; nn < 2; nn++)
    #pragma unroll
    for (int kk = 0; kk < 2; kk++) {
      int br = wc * 32 + nn * 16 + l16;
      boff[nn][kk] = 16384 + ((br * 128 + ((kk * 64 + lg * 16) ^ ((br & 7) << 4))) >> 1);
    }

  int rh = tid >> 3;
  int cc = (tid & 7) ^ (rh & 7);
  const u16* pA[4];
  #pragma unroll
  for (int u = 0; u < 4; u++)
    pA[u] = A + (size_t)(m0 + u * 64 + rh) * Kst + k0 + cc * 8;
  const u16* pB[4];
  #pragma unroll
  for (int u = 0; u < 4; u++) {
    if (GU) pB[u] = (u < 2 ? B1 + (size_t)(n0 + u * 64 + rh) * Kst
                           : B2 + (size_t)(n0 + (u - 2) * 64 + rh) * Kst) + k0 + cc * 8;
    else    pB[u] = B1 + (size_t)(n0 + u * 64 + rh) * Kst + k0 + cc * 8;
  }

  auto stA = [&](int tt, int h) {
    u16* d = lds + (tt & 1) * SLOT + h * 8192;
    gld16(pA[h * 2 + 0] + (size_t)tt * 64, d + tid * 8);
    gld16(pA[h * 2 + 1] + (size_t)tt * 64, d + 4096 + tid * 8);
  };
  auto stB = [&](int tt, int h) {
    u16* d = lds + (tt & 1) * SLOT + 16384 + h * 8192;
    gld16(pB[h * 2 + 0] + (size_t)tt * 64, d + tid * 8);
    gld16(pB[h * 2 + 1] + (size_t)tt * 64, d + 4096 + tid * 8);
  };

  stA(0, 0); stB(0, 0); stA(0, 1); stB(0, 1);
  stA(1, 0); stB(1, 0); stA(1, 1);
  VM(6);
  bar();

  f32x4 acc[8][4];
  f32x4 zero = {0.f, 0.f, 0.f, 0.f};
  #pragma unroll
  for (int m = 0; m < 8; m++)
    #pragma unroll
    for (int n = 0; n < 4; n++) acc[m][n] = zero;

  #pragma unroll 2
  for (int t = 0; t < NT; ++t) {
    u16* cur = lds + (t & 1) * SLOT;
    bf16x8 a0[4][2], a1[4][2], b0[2][2], b1[2][2];

    // ---- ph0: read A-mh0 + B-nh0 (12); stage B-h1(t+1); MFMA (mh0,nh0) ----
    #pragma unroll
    for (int mm = 0; mm < 4; mm++)
      #pragma unroll
      for (int kk = 0; kk < 2; kk++)
        a0[mm][kk] = *(const bf16x8*)(cur + aoff[mm][kk]);
    #pragma unroll
    for (int nn = 0; nn < 2; nn++)
      #pragma unroll
      for (int kk = 0; kk < 2; kk++)
        b0[nn][kk] = *(const bf16x8*)(cur + boff[nn][kk]);
    if (t + 1 < NT) stB(t + 1, 1);
    LG(8);
    bar();
    LG(0);
    SCHED0;
    __builtin_amdgcn_s_setprio(1);
    #pragma unroll
    for (int mm = 0; mm < 4; mm++)
      #pragma unroll
      for (int nn = 0; nn < 2; nn++)
        #pragma unroll
        for (int kk = 0; kk < 2; kk++)
          acc[mm][nn] = mfma16(a0[mm][kk], b0[nn][kk], acc[mm][nn]);
    __builtin_amdgcn_s_setprio(0);
    SCHED0;
    bar();

    // ---- ph1: read B-nh1 (4); stage A-h0(t+2); MFMA (mh0,nh1) ----
    #pragma unroll
    for (int nn = 0; nn < 2; nn++)
      #pragma unroll
      for (int kk = 0; kk < 2; kk++)
        b1[nn][kk] = *(const bf16x8*)(cur + boff[nn][kk] + 8192);
    if (t + 2 < NT) stA(t + 2, 0);
    bar();
    LG(0);
    SCHED0;
    __builtin_amdgcn_s_setprio(1);
    #pragma unroll
    for (int mm = 0; mm < 4; mm++)
      #pragma unroll
      for (int nn = 0; nn < 2; nn++)
        #pragma unroll
        for (int kk = 0; kk < 2; kk++)
          acc[mm][2 + nn] = mfma16(a0[mm][kk], b1[nn][kk], acc[mm][2 + nn]);
    __builtin_amdgcn_s_setprio(0);
    SCHED0;
    bar();

    // ---- ph2: read A-mh1 (8); stage B-h0(t+2); MFMA (mh1,nh0) ----
    #pragma unroll
    for (int mm = 0; mm < 4; mm++)
      #pragma unroll
      for (int kk = 0; kk < 2; kk++)
        a1[mm][kk] = *(const bf16x8*)(cur + aoff[mm][kk] + 8192);
    if (t + 2 < NT) stB(t + 2, 0);
    bar();
    LG(0);
    SCHED0;
    __builtin_amdgcn_s_setprio(1);
    #pragma unroll
    for (int mm = 0; mm < 4; mm++)
      #pragma unroll
      for (int nn = 0; nn < 2; nn++)
        #pragma unroll
        for (int kk = 0; kk < 2; kk++)
          acc[4 + mm][nn] = mfma16(a1[mm][kk], b0[nn][kk], acc[4 + mm][nn]);
    __builtin_amdgcn_s_setprio(0);
    SCHED0;
    bar();

    // ---- ph3: stage A-h1(t+2); VM(6); MFMA (mh1,nh1) ----
    if (t + 2 < NT) { stA(t + 2, 1); VM(6); }
    else if (t + 1 < NT) { VM(0); }
    bar();
    SCHED0;
    __builtin_amdgcn_s_setprio(1);
    #pragma unroll
    for (int mm = 0; mm < 4; mm++)
      #pragma unroll
      for (int nn = 0; nn < 2; nn++)
        #pragma unroll
        for (int kk = 0; kk < 2; kk++)
          acc[4 + mm][2 + nn] = mfma16(a1[mm][kk], b1[nn][kk], acc[4 + mm][2 + nn]);
    __builtin_amdgcn_s_setprio(0);
    SCHED0;
    bar();
  }

  if (GU) {
    #pragma unroll
    for (int m = 0; m < 8; m++) {
      int row = m0 + (m >> 2) * 128 + wr * 64 + (m & 3) * 16 + lg * 4;
      #pragma unroll
      for (int nn = 0; nn < 2; nn++) {
        int col = n0 + wc * 32 + nn * 16 + l16;
        #pragma unroll
        for (int r = 0; r < 4; r++) {
          float gt = acc[m][nn][r];
          float up = acc[m][2 + nn][r];
          float sg = gt / (1.0f + __expf(-gt));
          Cb[(size_t)(row + r) * N + col] = f2bf(sg * up);
        }
      }
    }
  } else {
    #pragma unroll
    for (int m = 0; m < 8; m++) {
      int row = m0 + (m >> 2) * 128 + wr * 64 + (m & 3) * 16 + lg * 4;
      #pragma unroll
      for (int n = 0; n < 4; n++) {
        int col = n0 + (n >> 1) * 128 + wc * 32 + (n & 1) * 16 + l16;
        #pragma unroll
        for (int r = 0; r < 4; r++) {
          size_t idx = (size_t)(row + r) * N + col;
          if (EPI == 0) Cb[idx] = f2bf(acc[m][n][r]);
          else          atomicAdd(Cf + idx, acc[m][n][r]);
        }
      }
    }
  }
}

// ------------- flash attention, sliding window + sink, dbuf staging ---------
// Q-RoPE + 1/sqrt(d) scale fused into the Q fragment load (in-register;
// each lane holds both halves of each RoPE pair: (kd, kd+2) <-> (d, d+64)).
__global__ __launch_bounds__(256)
void attn_k(const u16* __restrict__ qb, int ldq,
            const u16* __restrict__ kb, int ldk,
            const u16* __restrict__ vbt, u16* __restrict__ ao,
            const float* __restrict__ ct, const float* __restrict__ st)
{
  int q0 = blockIdx.x * 128;
  int h = blockIdx.y;
  int b = blockIdx.z;
  int hk = h >> 2;
  int tid = threadIdx.x;
  int w = tid >> 6, l = tid & 63;
  int l16 = l & 15, lg = l >> 4;

  __shared__ u16 Ks[2][32 * 128];
  __shared__ u16 Vt[2][128 * 32];
  __shared__ u16 Ps[4][32 * 40];
  u16* Pw = Ps[w];

  const float qscale = 0.08838834764831845f;
  bf16x8 qf[2][4];
  #pragma unroll
  for (int m = 0; m < 2; m++) {
    int row = q0 + w * 32 + m * 16 + l16;
    #pragma unroll
    for (int kd = 0; kd < 4; kd++)
      qf[m][kd] = *(const bf16x8*)(qb + (size_t)(b * SEQ + row) * ldq
                                   + h * HDIM + kd * 32 + lg * 8);
    const float* ctp = ct + (size_t)row * 64;
    const float* stp = st + (size_t)row * 64;
    #pragma unroll
    for (int pr = 0; pr < 2; pr++) {     // pair (kd=pr, kd=pr+2) = (d, d+64)
      bf16x8 lo = qf[m][pr], hi = qf[m][pr + 2];
      int dl = pr * 32 + lg * 8;
      #pragma unroll
      for (int j = 0; j < 8; j++) {
        float c = ctp[dl + j], s = stp[dl + j];
        float x1 = (float)lo[j], x2 = (float)hi[j];
        lo[j] = (__bf16)((x1 * c - x2 * s) * qscale);
        hi[j] = (__bf16)((x2 * c + x1 * s) * qscale);
      }
      qf[m][pr] = lo; qf[m][pr + 2] = hi;
    }
  }

  f32x4 oacc[2][8];
  float mrun[2][4], lrun[2][4];
  f32x4 zero = {0.f, 0.f, 0.f, 0.f};
  #pragma unroll
  for (int m = 0; m < 2; m++) {
    #pragma unroll
    for (int nd = 0; nd < 8; nd++) oacc[m][nd] = zero;
    #pragma unroll
    for (int r = 0; r < 4; r++) { mrun[m][r] = -1e9f; lrun[m][r] = 0.f; }
  }

  int kr0 = tid >> 4,        kc0 = (tid & 15) ^ (kr0 & 7);
  int kr1 = (tid + 256) >> 4, kc1 = (tid & 15) ^ (kr1 & 7);
  int vd0, vk0, vd1, vk1;
  swz_rc(tid, vd0, vk0);
  swz_rc(tid + 256, vd1, vk1);
  const u16* kbase = kb + (size_t)(b * SEQ) * ldk + hk * HDIM;
  const u16* vbase = vbt + (size_t)(b * NKV + hk) * HDIM * SEQ;

  int koff[2][4];
  #pragma unroll
  for (int n = 0; n < 2; n++)
    #pragma unroll
    for (int kd = 0; kd < 4; kd++) {
      int key = n * 16 + l16;
      koff[n][kd] = ((key * 128) + kd * 32 + lg * 8) ^ ((key & 7) * 8);
    }
  int voff[8];
  #pragma unroll
  for (int nd = 0; nd < 8; nd++) {
    int d = nd * 16 + l16;
    voff[nd] = (d * 32 + lg * 8) ^ ((d & 7) * 8);
  }

  auto stage = [&](int kt, int bsel) {
    gld16(kbase + (size_t)(kt * 32 + kr0) * ldk + kc0 * 8, Ks[bsel] + tid * 8);
    gld16(kbase + (size_t)(kt * 32 + kr1) * ldk + kc1 * 8, Ks[bsel] + (tid + 256) * 8);
    gld16(vbase + (size_t)vd0 * SEQ + kt * 32 + vk0 * 8, Vt[bsel] + tid * 8);
    gld16(vbase + (size_t)vd1 * SEQ + kt * 32 + vk1 * 8, Vt[bsel] + (tid + 256) * 8);
  };

  int lo = (q0 >= WIN) ? ((q0 - (WIN - 1)) >> 5) : 0;
  int hi = (q0 + 127) >> 5;
  int it0 = (lo > 0 ? lo - 1 : 0);

  stage((it0 < lo) ? 0 : it0, 0);
  int bsel = 0;

  for (int it = it0; it <= hi; ++it) {
    int kt = (it < lo) ? 0 : it;
    if (it < hi) { stage(it + 1, bsel ^ 1); VM(4); }
    else         { VM(0); }
    bar();
    const u16* Ksb = Ks[bsel];
    const u16* Vtb = Vt[bsel];

    f32x4 sacc[2][2];
    sacc[0][0] = zero; sacc[0][1] = zero; sacc[1][0] = zero; sacc[1][1] = zero;
    #pragma unroll
    for (int kd = 0; kd < 4; kd++) {
      bf16x8 kf0 = *(const bf16x8*)(Ksb + koff[0][kd]);
      bf16x8 kf1 = *(const bf16x8*)(Ksb + koff[1][kd]);
      #pragma unroll
      for (int m = 0; m < 2; m++) {
        sacc[m][0] = mfma16(qf[m][kd], kf0, sacc[m][0]);
        sacc[m][1] = mfma16(qf[m][kd], kf1, sacc[m][1]);
      }
    }

    #pragma unroll
    for (int m = 0; m < 2; m++) {
      float sc[4];
      #pragma unroll
      for (int r = 0; r < 4; r++) {
        int i = q0 + w * 32 + m * 16 + lg * 4 + r;
        int j0 = kt * 32 + l16;
        int j1 = j0 + 16;
        float s0 = sacc[m][0][r];
        float s1 = sacc[m][1][r];
        bool ok0 = (j0 <= i) && ((i - j0 < WIN) || (j0 < SINKN));
        bool ok1 = (j1 <= i) && ((i - j1 < WIN) || (j1 < SINKN));
        s0 = ok0 ? s0 : -1e9f;
        s1 = ok1 ? s1 : -1e9f;
        float mx = fmaxf(s0, s1);
        mx = fmaxf(mx, __shfl_xor(mx, 1));
        mx = fmaxf(mx, __shfl_xor(mx, 2));
        mx = fmaxf(mx, __shfl_xor(mx, 4));
        mx = fmaxf(mx, __shfl_xor(mx, 8));
        float mold = mrun[m][r];
        float mnew = fmaxf(mold, mx);
        float scl = __expf(mold - mnew);
        mrun[m][r] = mnew;
        float p0 = __expf(s0 - mnew);
        float p1 = __expf(s1 - mnew);
        int prow = m * 16 + lg * 4 + r;
        Pw[prow * 40 + l16] = f2bf(p0);
        Pw[prow * 40 + 16 + l16] = f2bf(p1);
        float ps = p0 + p1;
        ps += __shfl_xor(ps, 1);
        ps += __shfl_xor(ps, 2);
        ps += __shfl_xor(ps, 4);
        ps += __shfl_xor(ps, 8);
        lrun[m][r] = lrun[m][r] * scl + ps;
        sc[r] = scl;
      }
      #pragma unroll
      for (int nd = 0; nd < 8; nd++) {
        oacc[m][nd][0] *= sc[0];
        oacc[m][nd][1] *= sc[1];
        oacc[m][nd][2] *= sc[2];
        oacc[m][nd][3] *= sc[3];
      }
    }

    bf16x8 pa0 = *(const bf16x8*)(Pw + l16 * 40 + lg * 8);
    bf16x8 pa1 = *(const bf16x8*)(Pw + (16 + l16) * 40 + lg * 8);
    #pragma unroll
    for (int nd = 0; nd < 8; nd++) {
      bf16x8 vf = *(const bf16x8*)(Vtb + voff[nd]);
      oacc[0][nd] = mfma16(pa0, vf, oacc[0][nd]);
      oacc[1][nd] = mfma16(pa1, vf, oacc[1][nd]);
    }
    bar();
    bsel ^= 1;
  }

  #pragma unroll
  for (int m = 0; m < 2; m++)
    #pragma unroll
    for (int r = 0; r < 4; r++) {
      float invl = 1.0f / lrun[m][r];
      int row = q0 + w * 32 + m * 16 + lg * 4 + r;
      #pragma unroll
      for (int nd = 0; nd < 8; nd++) {
        int col = nd * 16 + l16;
        ao[(size_t)(b * SEQ + row) * (NH * HDIM) + h * HDIM + col] =
            f2bf(oacc[m][nd][r] * invl);
      }
    }
}

// ------------------------------- launcher -----------------------------------
extern "C" void kernel_launch(void* const* d_in, const int* in_sizes, int n_in,
                              void* d_out, int out_size, void* d_ws, size_t ws_size,
                              hipStream_t stream)
{
  (void)in_sizes; (void)n_in; (void)out_size;
  const float* x  = (const float*)d_in[0];
  const float* g1 = (const float*)d_in[1];
  const float* g2 = (const float*)d_in[2];
  const float* wq = (const float*)d_in[3];
  const float* wk = (const float*)d_in[4];
  const float* wv = (const float*)d_in[5];
  const float* wo = (const float*)d_in[6];
  const float* wg = (const float*)d_in[7];
  const float* wu = (const float*)d_in[8];
  const float* wd = (const float*)d_in[9];
  float* out = (float*)d_out;

  char* ws = (char*)d_ws;
  size_t off = 0;
  auto alloc = [&](size_t bytes) {
    char* p = ws + off;
    off += (bytes + 255) & ~(size_t)255;
    return p;
  };
  const int NQKV = 3072;   // q 0..2047 | k 2048..2559 | v 2560..3071
  u16* wqkv_t = (u16*)alloc((size_t)NQKV * DM * 2);
  u16* wo_t   = (u16*)alloc((size_t)DM * DM * 2);
  u16* wg_t   = (u16*)alloc((size_t)HID * DM * 2);
  u16* wu_t   = (u16*)alloc((size_t)HID * DM * 2);
  u16* wd_t   = (u16*)alloc((size_t)DM * HID * 2);
  u16* hb     = (u16*)alloc((size_t)TOK * DM * 2);
  // gu (67.1 MB) aliases qkvb+vbt+aob (dead by the time gateup runs) + tail
  char* span0 = ws + off;
  u16* qkvb   = (u16*)alloc((size_t)TOK * NQKV * 2);
  u16* vbt    = (u16*)alloc((size_t)TOK * NKV * HDIM * 2);
  u16* aob    = (u16*)alloc((size_t)TOK * NH * HDIM * 2);
  size_t span_used = (size_t)(ws + off - span0);
  size_t gu_need = (size_t)TOK * HID * 2;
  if (gu_need > span_used) alloc(gu_need - span_used);
  u16* gu = (u16*)span0;
  float* ct  = (float*)alloc((size_t)SEQ * 64 * 4);
  float* st  = (float*)alloc((size_t)SEQ * 64 * 4);
  if (off > ws_size) return;

  dim3 blk(256);
  dim3 blk512(512);

  wtrans_all<<<dim3(59392), blk, 0, stream>>>(wq, wk, wv, wo, wg, wu, wd,
                                              wqkv_t, wo_t, wg_t, wu_t, wd_t);

  rope_table_k<<<SEQ * 64 / 256, blk, 0, stream>>>(ct, st);
  rmsnorm_k<<<TOK, blk, 0, stream>>>(x, g1, hb);

  // fused QKV projection: [4096][3072] (192 blocks)
  gemm256<0, 0, 0><<<dim3((NQKV / 256) * (TOK / 256)), blk512, 0, stream>>>(
      hb, wqkv_t, nullptr, qkvb, nullptr, DM, DM / 64, NQKV, NQKV / 256);

  // K rope only (Q rope fused into attn)
  rope_apply_k<<<TOK, dim3(NKV * 64), 0, stream>>>(qkvb + DM, NQKV, ct, st, 1.0f);
  vtrans<<<dim3((NKV * HDIM) / 32, TOK / 32), blk, 0, stream>>>(qkvb + DM + NKV * HDIM, NQKV, vbt);

  attn_k<<<dim3(SEQ / 128, NH, 2), blk, 0, stream>>>(qkvb, NQKV, qkvb + DM, NQKV, vbt, aob, ct, st);

  // wo: out = x + aob @ wo^T (no atomics)
  gemmp<1><<<dim3((DM / 256) * (TOK / 128)), blk512, 0, stream>>>(
      aob, wo_t, nullptr, out, x, TOK, DM, DM, DM / 256);
  rmsnorm_k<<<TOK, blk, 0, stream>>>(out, g2, hb);

  // fused gate+up with silu epilogue (1024 blocks)
  gemm256<0, 1, 0><<<dim3((HID / 128) * (TOK / 256)), blk512, 0, stream>>>(
      hb, wg_t, wu_t, gu, nullptr, DM, DM / 64, HID, HID / 128);

  // down-proj: split-K=2, atomicAdd into out (256 blocks)
  gemm256<4, 0, 1><<<dim3(2 * (DM / 256) * (TOK / 256)), blk512, 0, stream>>>(
      gu, wd_t, nullptr, nullptr, out, HID, HID / 128, DM, DM / 256);
}

// Round 15
// 731.016 us; speedup vs baseline: 1.0079x; 1.0079x over previous
//
#include <hip/hip_runtime.h>
#include <hip/hip_bf16.h>
#include <stdint.h>

#define TOK 4096
#define SEQ 2048
#define DM 2048
#define NH 16
#define NKV 4
#define HDIM 128
#define HID 8192
#define WIN 1024
#define SINKN 4

typedef float f32x4 __attribute__((ext_vector_type(4)));
typedef __bf16 bf16x8 __attribute__((ext_vector_type(8)));
typedef unsigned short u16;
typedef unsigned int u32;

#define VM(n) asm volatile("s_waitcnt vmcnt(" #n ")" ::: "memory")
#define LG(n) asm volatile("s_waitcnt lgkmcnt(" #n ")" ::: "memory")
#define SCHED0 __builtin_amdgcn_sched_barrier(0)

__device__ __forceinline__ u16 f2bf(float f) {
  union { float f; u32 u; } v; v.f = f;
  return (u16)((v.u + 0x7fffu + ((v.u >> 16) & 1u)) >> 16);
}
__device__ __forceinline__ float bf2f(u16 h) {
  union { u32 u; float f; } v; v.u = ((u32)h) << 16;
  return v.f;
}
__device__ __forceinline__ f32x4 mfma16(bf16x8 a, bf16x8 b, f32x4 c) {
  return __builtin_amdgcn_mfma_f32_16x16x32_bf16(a, b, c, 0, 0, 0);
}
__device__ __forceinline__ void gld16(const u16* g, u16* l) {
  __builtin_amdgcn_global_load_lds(
      (const __attribute__((address_space(1))) u32*)g,
      (__attribute__((address_space(3))) u32*)l, 16, 0, 0);
}
__device__ __forceinline__ void bar() {
  asm volatile("s_barrier" ::: "memory");
}
// Inverse swizzle for 64B-row tiles ([rows][32] u16) used by attn staging.
__device__ __forceinline__ void swz_rc(int c, int& row, int& k8) {
  row = 2 * (c >> 3) + (((c >> 2) & 1) ^ ((c >> 4) & 1));
  k8 = (c & 3) ^ (row & 3);
}
// XCD-chunked + grouped raster (G=8).
__device__ __forceinline__ void raster8(int wg, int nwg, int nbx, int& bx, int& by) {
  int cpx = nwg >> 3;
  int s = (wg & 7) * cpx + (wg >> 3);
  by = 8 * (s / (8 * nbx)) + (s & 7);
  bx = (s >> 3) % nbx;
}

// ---- merged setup: weight transposes + rope table + rmsnorm1 ---------------
// blocks [0,59392): wtrans segments; [59392,59904): rope table;
// [59904,64000): rmsnorm rows.
__global__ __launch_bounds__(256)
void setup_all(const float* __restrict__ wq, const float* __restrict__ wk,
               const float* __restrict__ wv, const float* __restrict__ wo,
               const float* __restrict__ wg, const float* __restrict__ wu,
               const float* __restrict__ wd,
               u16* __restrict__ dqkv, u16* __restrict__ dwo,
               u16* __restrict__ dwg, u16* __restrict__ dwu,
               u16* __restrict__ dwd,
               float* __restrict__ ct, float* __restrict__ st,
               const float* __restrict__ x, const float* __restrict__ g1,
               u16* __restrict__ hb)
{
  int id = blockIdx.x;
  int tid = threadIdx.x;
  __shared__ float t[32][33];

  if (id >= 59904) {                       // ---- rmsnorm1 ----
    int row = id - 59904;
    const float* xr = x + (size_t)row * DM;
    float4 v0 = *(const float4*)(xr + tid * 8);
    float4 v1 = *(const float4*)(xr + tid * 8 + 4);
    float ss = v0.x*v0.x + v0.y*v0.y + v0.z*v0.z + v0.w*v0.w
             + v1.x*v1.x + v1.y*v1.y + v1.z*v1.z + v1.w*v1.w;
    #pragma unroll
    for (int d = 1; d < 64; d <<= 1) ss += __shfl_xor(ss, d);
    float* red = &t[0][0];
    if ((tid & 63) == 0) red[tid >> 6] = ss;
    __syncthreads();
    float inv = rsqrtf((red[0] + red[1] + red[2] + red[3]) * (1.0f / DM) + 1e-6f);
    float4 q0 = *(const float4*)(g1 + tid * 8);
    float4 q1 = *(const float4*)(g1 + tid * 8 + 4);
    ushort4 o0, o1;
    o0.x = f2bf(v0.x * inv * q0.x); o0.y = f2bf(v0.y * inv * q0.y);
    o0.z = f2bf(v0.z * inv * q0.z); o0.w = f2bf(v0.w * inv * q0.w);
    o1.x = f2bf(v1.x * inv * q1.x); o1.y = f2bf(v1.y * inv * q1.y);
    o1.z = f2bf(v1.z * inv * q1.z); o1.w = f2bf(v1.w * inv * q1.w);
    *(ushort4*)(hb + (size_t)row * DM + tid * 8) = o0;
    *(ushort4*)(hb + (size_t)row * DM + tid * 8 + 4) = o1;
    return;
  }
  if (id >= 59392) {                       // ---- rope table ----
    int idx = (id - 59392) * 256 + tid;    // 2048*64
    int pos = idx >> 6, d = idx & 63;
    float inv = powf(10000.0f, -(float)d / 64.0f);
    float a = (float)pos * inv;
    ct[idx] = cosf(a);
    st[idx] = sinf(a);
    return;
  }
  // ---- weight transpose ----
  const float* src; u16* dst; int K, N, lgn;
  if (id < 4096)       { src = wq; dst = dqkv;                        K = 2048; N = 2048; lgn = 6; }
  else if (id < 5120)  { id -= 4096;  src = wk; dst = dqkv + (size_t)DM * DM;          K = 2048; N = 512;  lgn = 4; }
  else if (id < 6144)  { id -= 5120;  src = wv; dst = dqkv + (size_t)(DM + 512) * DM;  K = 2048; N = 512;  lgn = 4; }
  else if (id < 10240) { id -= 6144;  src = wo; dst = dwo;            K = 2048; N = 2048; lgn = 6; }
  else if (id < 26624) { id -= 10240; src = wg; dst = dwg;            K = 2048; N = 8192; lgn = 8; }
  else if (id < 43008) { id -= 26624; src = wu; dst = dwu;            K = 2048; N = 8192; lgn = 8; }
  else                 { id -= 43008; src = wd; dst = dwd;            K = 8192; N = 2048; lgn = 6; }
  int bx = id & ((1 << lgn) - 1);
  int by = id >> lgn;
  int tx = tid & 31, ty = tid >> 5;
  #pragma unroll
  for (int i = 0; i < 4; i++) {
    int r = ty + i * 8;
    t[r][tx] = src[(size_t)(by * 32 + r) * N + bx * 32 + tx];
  }
  __syncthreads();
  #pragma unroll
  for (int i = 0; i < 4; i++) {
    int r = ty + i * 8;
    dst[(size_t)(bx * 32 + r) * K + by * 32 + tx] = f2bf(t[tx][r]);
  }
}

// ---- merged K-rope + V-transpose (both on qkv output) ----------------------
// blocks [0,4096): K rope in place; [4096,6144): V cols -> vbt rows.
__global__ __launch_bounds__(256)
void kv_post(u16* __restrict__ qkvb, const float* __restrict__ ct,
             const float* __restrict__ st, u16* __restrict__ vbt)
{
  const int NQKV = 3072;
  int id = blockIdx.x;
  int tid = threadIdx.x;
  if (id < 4096) {                          // K rope
    int tt = id;
    int hh = tid >> 6;
    int d = tid & 63;
    int pos = tt & (SEQ - 1);
    size_t base = (size_t)tt * NQKV + DM + hh * HDIM + d;
    float x1 = bf2f(qkvb[base]), x2 = bf2f(qkvb[base + 64]);
    float c = ct[pos * 64 + d], s = st[pos * 64 + d];
    qkvb[base]      = f2bf(x1 * c - x2 * s);
    qkvb[base + 64] = f2bf(x2 * c + x1 * s);
    return;
  }
  // V transpose
  id -= 4096;
  int bx = id & 15, by = id >> 4;
  const u16* in = qkvb + DM + NKV * HDIM;
  __shared__ u16 t[32][33];
  int tx = tid & 31, ty = tid >> 5;
  #pragma unroll
  for (int i = 0; i < 4; i++) {
    int r = ty + i * 8;
    t[r][tx] = in[(size_t)(by * 32 + r) * NQKV + bx * 32 + tx];
  }
  __syncthreads();
  int b = (by * 32) >> 11;
  int s0 = (by * 32) & (SEQ - 1);
  #pragma unroll
  for (int i = 0; i < 4; i++) {
    int c = bx * 32 + ty + i * 8;
    vbt[(size_t)(b * (NKV * HDIM) + c) * SEQ + s0 + tx] = t[tx][ty + i * 8];
  }
}

// ------------------------------ RMSNorm ------------------------------------
__global__ __launch_bounds__(256)
void rmsnorm_k(const float* __restrict__ x, const float* __restrict__ g,
               u16* __restrict__ o)
{
  int row = blockIdx.x;
  int tid = threadIdx.x;
  const float* xr = x + (size_t)row * DM;
  float4 v0 = *(const float4*)(xr + tid * 8);
  float4 v1 = *(const float4*)(xr + tid * 8 + 4);
  float ss = v0.x*v0.x + v0.y*v0.y + v0.z*v0.z + v0.w*v0.w
           + v1.x*v1.x + v1.y*v1.y + v1.z*v1.z + v1.w*v1.w;
  #pragma unroll
  for (int d = 1; d < 64; d <<= 1) ss += __shfl_xor(ss, d);
  __shared__ float red[4];
  if ((tid & 63) == 0) red[tid >> 6] = ss;
  __syncthreads();
  float inv = rsqrtf((red[0] + red[1] + red[2] + red[3]) * (1.0f / DM) + 1e-6f);
  float4 g0 = *(const float4*)(g + tid * 8);
  float4 g1 = *(const float4*)(g + tid * 8 + 4);
  ushort4 o0, o1;
  o0.x = f2bf(v0.x * inv * g0.x); o0.y = f2bf(v0.y * inv * g0.y);
  o0.z = f2bf(v0.z * inv * g0.z); o0.w = f2bf(v0.w * inv * g0.w);
  o1.x = f2bf(v1.x * inv * g1.x); o1.y = f2bf(v1.y * inv * g1.y);
  o1.z = f2bf(v1.z * inv * g1.z); o1.w = f2bf(v1.w * inv * g1.w);
  *(ushort4*)(o + (size_t)row * DM + tid * 8) = o0;
  *(ushort4*)(o + (size_t)row * DM + tid * 8 + 4) = o1;
}

// ------------- deep-pipelined GEMM: 128 x 256, BK=64, 3-slot ring -----------
// (wo path: EPI=1 -> Cf = X + acc, no atomics)
template<int EPI>
__global__ __launch_bounds__(512, 1)
void gemmp(const u16* __restrict__ A, const u16* __restrict__ Bt,
           u16* __restrict__ Cb, float* __restrict__ Cf,
           const float* __restrict__ X, int M, int N, int K, int nbx)
{
  constexpr int ASZ = 128 * 64;
  constexpr int SLOT = ASZ + 256 * 64;
  __shared__ u16 lds[3 * SLOT];

  int bx, by;
  raster8(blockIdx.x, gridDim.x, nbx, bx, by);
  int m0 = by * 128;
  int n0 = bx * 256;

  int tid = threadIdx.x;
  int l = tid & 63, w = tid >> 6;
  int l16 = l & 15, lg = l >> 4;
  int wr = w >> 2, wc = w & 3;

  int aoff[4][2], boff[4][2];
  #pragma unroll
  for (int m = 0; m < 4; m++)
    #pragma unroll
    for (int kk = 0; kk < 2; kk++) {
      int row = wr * 64 + m * 16 + l16;
      aoff[m][kk] = ((row * 128 + kk * 64 + lg * 16) ^ ((row & 7) << 4)) >> 1;
    }
  #pragma unroll
  for (int n = 0; n < 4; n++)
    #pragma unroll
    for (int kk = 0; kk < 2; kk++) {
      int br = wc * 64 + n * 16 + l16;
      boff[n][kk] = ASZ + (((br * 128 + kk * 64 + lg * 16) ^ ((br & 7) << 4)) >> 1);
    }

  int urow = tid >> 3;
  int cc = (tid & 7) ^ (urow & 7);
  const u16* pA[2];
  const u16* pB[4];
  pA[0] = A + (size_t)(m0 + urow) * K + cc * 8;
  pA[1] = A + (size_t)(m0 + 64 + urow) * K + cc * 8;
  #pragma unroll
  for (int u = 0; u < 4; u++)
    pB[u] = Bt + (size_t)(n0 + u * 64 + urow) * K + cc * 8;

  const int NT = K >> 6;

  auto stA = [&](int tt, int u) {
    gld16(pA[u] + (size_t)tt * 64, lds + (tt % 3) * SLOT + u * 4096 + tid * 8);
  };
  auto stB = [&](int tt, int u) {
    gld16(pB[u] + (size_t)tt * 64, lds + (tt % 3) * SLOT + ASZ + u * 4096 + tid * 8);
  };

  #pragma unroll
  for (int u = 0; u < 4; u++) stB(0, u);
  stA(0, 0); stA(0, 1);
  #pragma unroll
  for (int u = 0; u < 4; u++) stB(1, u);
  stA(1, 0); stA(1, 1);
  VM(6);
  bar();

  f32x4 acc[4][4];
  f32x4 zero = {0.f, 0.f, 0.f, 0.f};
  #pragma unroll
  for (int m = 0; m < 4; m++)
    #pragma unroll
    for (int n = 0; n < 4; n++) acc[m][n] = zero;

  for (int t = 0; t < NT; ++t) {
    u16* cur = lds + (t % 3) * SLOT;
    const bool st = (t + 2 < NT);

    if (st) { stB(t + 2, 0); stB(t + 2, 1); stB(t + 2, 2); }
    bf16x8 a[4][2], b[2][2], c2[2][2];
    #pragma unroll
    for (int m = 0; m < 4; m++) {
      a[m][0] = *(const bf16x8*)(cur + aoff[m][0]);
      a[m][1] = *(const bf16x8*)(cur + aoff[m][1]);
    }
    #pragma unroll
    for (int n = 0; n < 2; n++) {
      b[n][0] = *(const bf16x8*)(cur + boff[n][0]);
      b[n][1] = *(const bf16x8*)(cur + boff[n][1]);
    }
    SCHED0;
    #pragma unroll
    for (int n = 0; n < 2; n++) {
      c2[n][0] = *(const bf16x8*)(cur + boff[n + 2][0]);
      c2[n][1] = *(const bf16x8*)(cur + boff[n + 2][1]);
    }
    bar();
    LG(4);
    SCHED0;
    __builtin_amdgcn_s_setprio(1);
    #pragma unroll
    for (int m = 0; m < 4; m++)
      #pragma unroll
      for (int n = 0; n < 2; n++) {
        acc[m][n] = mfma16(a[m][0], b[n][0], acc[m][n]);
        acc[m][n] = mfma16(a[m][1], b[n][1], acc[m][n]);
      }
    __builtin_amdgcn_s_setprio(0);
    SCHED0;
    bar();

    if (st) { stB(t + 2, 3); stA(t + 2, 0); stA(t + 2, 1); }
    if (st) { VM(6); }
    else if (t + 1 < NT) { VM(0); }
    bar();
    LG(0);
    SCHED0;
    __builtin_amdgcn_s_setprio(1);
    #pragma unroll
    for (int m = 0; m < 4; m++)
      #pragma unroll
      for (int n = 0; n < 2; n++) {
        acc[m][n + 2] = mfma16(a[m][0], c2[n][0], acc[m][n + 2]);
        acc[m][n + 2] = mfma16(a[m][1], c2[n][1], acc[m][n + 2]);
      }
    __builtin_amdgcn_s_setprio(0);
    SCHED0;
    bar();
  }

  #pragma unroll
  for (int m = 0; m < 4; m++) {
    int row = m0 + wr * 64 + m * 16 + lg * 4;
    #pragma unroll
    for (int n = 0; n < 4; n++) {
      int col = n0 + wc * 64 + n * 16 + l16;
      #pragma unroll
      for (int r = 0; r < 4; r++) {
        size_t idx = (size_t)(row + r) * N + col;
        float v = acc[m][n][r];
        if (EPI == 0) {
          Cb[idx] = f2bf(v);
        } else if (EPI == 1) {
          Cf[idx] = X[idx] + v;
        } else {
          Cf[idx] += v;
        }
      }
    }
  }
}

// ---- 256x256 GEMM, single-barrier 4-phase: BK=64, 2-slot -------------------
// Phase = { ds_reads -> LG(0) -> [VM] -> bar -> stage -> 16 MFMA }.
// LG(0) pre-bar => at barrier-crossing ALL waves' reads retired, so post-bar
// stages cannot race reads (each stage's target region last read >=1 barrier
// before stage issue; verified per region). Stages interleave with MFMA.
// FIFO ledger (2 loads per stage): stages B-h1(t+1)@ph0, A-h0(t+2)@ph1,
// B-h0(t+2)@ph2, A-h1(t+2)@ph3 (all post-bar).
//  VM(6)@ph0 pre-bar: retires through B-h1(t)   [needed by ph1(t) reads]
//  VM(8)@ph3 pre-bar: retires through B-h0(t+1) [needed by ph0(t+1) reads]
// Prologue: A-h0(0),B-h0(0),A-h1(0),B-h1(0),A-h0(1),B-h0(1),A-h1(1) = 14
// loads, VM(8) -> tile-0 h0 halves landed. Never 0 mid-loop.
// EPI: 0 bf16 store, 4 atomicAdd fp32 (split-K). GU=1: B = gate|up, silu.
template<int EPI, int GU, int SPLITK>
__global__ __launch_bounds__(512, 1)
void gemm256(const u16* __restrict__ A, const u16* __restrict__ B1,
             const u16* __restrict__ B2, u16* __restrict__ Cb,
             float* __restrict__ Cf, int Kst, int NT, int N, int nbx)
{
  constexpr int SLOT = 32768;          // u16: A-h0|A-h1|B-h0|B-h1, 8192 each
  __shared__ u16 lds[2 * SLOT];        // 128 KiB

  int wg = blockIdx.x;
  int nwg = gridDim.x;
  int kh = 0;
  if (SPLITK) { int half = nwg >> 1; kh = (wg >= half); wg -= kh * half; nwg = half; }
  int bx, by;
  raster8(wg, nwg, nbx, bx, by);
  int m0 = by * 256;
  int n0 = bx * (GU ? 128 : 256);
  size_t k0 = (size_t)kh * NT * 64;

  int tid = threadIdx.x;
  int l = tid & 63, w = tid >> 6;
  int l16 = l & 15, lg = l >> 4;
  int wr = w >> 2, wc = w & 3;

  int aoff[4][2], boff[2][2];
  #pragma unroll
  for (int mm = 0; mm < 4; mm++)
    #pragma unroll
    for (int kk = 0; kk < 2; kk++) {
      int ar = wr * 64 + mm * 16 + l16;
      aoff[mm][kk] = ((ar * 128 + ((kk * 64 + lg * 16) ^ ((ar & 7) << 4))) >> 1);
    }
  #pragma unroll
  for (int nn = 0; nn < 2; nn++)
    #pragma unroll
    for (int kk = 0; kk < 2; kk++) {
      int br = wc * 32 + nn * 16 + l16;
      boff[nn][kk] = 16384 + ((br * 128 + ((kk * 64 + lg * 16) ^ ((br & 7) << 4))) >> 1);
    }

  int rh = tid >> 3;
  int cc = (tid & 7) ^ (rh & 7);
  const u16* pA[4];
  #pragma unroll
  for (int u = 0; u < 4; u++)
    pA[u] = A + (size_t)(m0 + u * 64 + rh) * Kst + k0 + cc * 8;
  const u16* pB[4];
  #pragma unroll
  for (int u = 0; u < 4; u++) {
    if (GU) pB[u] = (u < 2 ? B1 + (size_t)(n0 + u * 64 + rh) * Kst
                           : B2 + (size_t)(n0 + (u - 2) * 64 + rh) * Kst) + k0 + cc * 8;
    else    pB[u] = B1 + (size_t)(n0 + u * 64 + rh) * Kst + k0 + cc * 8;
  }

  auto stA = [&](int tt, int h) {
    u16* d = lds + (tt & 1) * SLOT + h * 8192;
    gld16(pA[h * 2 + 0] + (size_t)tt * 64, d + tid * 8);
    gld16(pA[h * 2 + 1] + (size_t)tt * 64, d + 4096 + tid * 8);
  };
  auto stB = [&](int tt, int h) {
    u16* d = lds + (tt & 1) * SLOT + 16384 + h * 8192;
    gld16(pB[h * 2 + 0] + (size_t)tt * 64, d + tid * 8);
    gld16(pB[h * 2 + 1] + (size_t)tt * 64, d + 4096 + tid * 8);
  };

  // prologue (14 loads): tile0 all halves + tile1 {A-h0, B-h0, A-h1}
  stA(0, 0); stB(0, 0); stA(0, 1); stB(0, 1);
  stA(1, 0); stB(1, 0); stA(1, 1);
  VM(8);     // retires A-h0(0),B-h0(0),A-h1(0): tile-0 read targets landed
  bar();

  f32x4 acc[8][4];
  f32x4 zero = {0.f, 0.f, 0.f, 0.f};
  #pragma unroll
  for (int m = 0; m < 8; m++)
    #pragma unroll
    for (int n = 0; n < 4; n++) acc[m][n] = zero;

  #pragma unroll 2
  for (int t = 0; t < NT; ++t) {
    u16* cur = lds + (t & 1) * SLOT;
    bf16x8 a0[4][2], a1[4][2], b0[2][2], b1[2][2];

    // ---- ph0: read A-mh0 + B-nh0; LG0; VM(6); bar; stage B-h1(t+1); MFMA --
    #pragma unroll
    for (int mm = 0; mm < 4; mm++)
      #pragma unroll
      for (int kk = 0; kk < 2; kk++)
        a0[mm][kk] = *(const bf16x8*)(cur + aoff[mm][kk]);
    #pragma unroll
    for (int nn = 0; nn < 2; nn++)
      #pragma unroll
      for (int kk = 0; kk < 2; kk++)
        b0[nn][kk] = *(const bf16x8*)(cur + boff[nn][kk]);
    LG(0);
    if (t + 1 < NT) { VM(6); } else { VM(0); }
    bar();
    if (t + 1 < NT) stB(t + 1, 1);
    SCHED0;
    __builtin_amdgcn_s_setprio(1);
    #pragma unroll
    for (int mm = 0; mm < 4; mm++)
      #pragma unroll
      for (int nn = 0; nn < 2; nn++)
        #pragma unroll
        for (int kk = 0; kk < 2; kk++)
          acc[mm][nn] = mfma16(a0[mm][kk], b0[nn][kk], acc[mm][nn]);
    __builtin_amdgcn_s_setprio(0);
    SCHED0;

    // ---- ph1: read B-nh1; LG0; bar; stage A-h0(t+2); MFMA (mh0,nh1) ----
    #pragma unroll
    for (int nn = 0; nn < 2; nn++)
      #pragma unroll
      for (int kk = 0; kk < 2; kk++)
        b1[nn][kk] = *(const bf16x8*)(cur + boff[nn][kk] + 8192);
    LG(0);
    bar();
    if (t + 2 < NT) stA(t + 2, 0);
    SCHED0;
    __builtin_amdgcn_s_setprio(1);
    #pragma unroll
    for (int mm = 0; mm < 4; mm++)
      #pragma unroll
      for (int nn = 0; nn < 2; nn++)
        #pragma unroll
        for (int kk = 0; kk < 2; kk++)
          acc[mm][2 + nn] = mfma16(a0[mm][kk], b1[nn][kk], acc[mm][2 + nn]);
    __builtin_amdgcn_s_setprio(0);
    SCHED0;

    // ---- ph2: read A-mh1; LG0; bar; stage B-h0(t+2); MFMA (mh1,nh0) ----
    #pragma unroll
    for (int mm = 0; mm < 4; mm++)
      #pragma unroll
      for (int kk = 0; kk < 2; kk++)
        a1[mm][kk] = *(const bf16x8*)(cur + aoff[mm][kk] + 8192);
    LG(0);
    bar();
    if (t + 2 < NT) stB(t + 2, 0);
    SCHED0;
    __builtin_amdgcn_s_setprio(1);
    #pragma unroll
    for (int mm = 0; mm < 4; mm++)
      #pragma unroll
      for (int nn = 0; nn < 2; nn++)
        #pragma unroll
        for (int kk = 0; kk < 2; kk++)
          acc[4 + mm][nn] = mfma16(a1[mm][kk], b0[nn][kk], acc[4 + mm][nn]);
    __builtin_amdgcn_s_setprio(0);
    SCHED0;

    // ---- ph3: VM(8); bar; stage A-h1(t+2); MFMA (mh1,nh1) ----
    if (t + 2 < NT) { VM(8); } else { VM(0); }
    bar();
    if (t + 2 < NT) stA(t + 2, 1);
    SCHED0;
    __builtin_amdgcn_s_setprio(1);
    #pragma unroll
    for (int mm = 0; mm < 4; mm++)
      #pragma unroll
      for (int nn = 0; nn < 2; nn++)
        #pragma unroll
        for (int kk = 0; kk < 2; kk++)
          acc[4 + mm][2 + nn] = mfma16(a1[mm][kk], b1[nn][kk], acc[4 + mm][2 + nn]);
    __builtin_amdgcn_s_setprio(0);
    SCHED0;
  }

  if (GU) {
    #pragma unroll
    for (int m = 0; m < 8; m++) {
      int row = m0 + (m >> 2) * 128 + wr * 64 + (m & 3) * 16 + lg * 4;
      #pragma unroll
      for (int nn = 0; nn < 2; nn++) {
        int col = n0 + wc * 32 + nn * 16 + l16;
        #pragma unroll
        for (int r = 0; r < 4; r++) {
          float gt = acc[m][nn][r];
          float up = acc[m][2 + nn][r];
          float sg = gt / (1.0f + __expf(-gt));
          Cb[(size_t)(row + r) * N + col] = f2bf(sg * up);
        }
      }
    }
  } else {
    #pragma unroll
    for (int m = 0; m < 8; m++) {
      int row = m0 + (m >> 2) * 128 + wr * 64 + (m & 3) * 16 + lg * 4;
      #pragma unroll
      for (int n = 0; n < 4; n++) {
        int col = n0 + (n >> 1) * 128 + wc * 32 + (n & 1) * 16 + l16;
        #pragma unroll
        for (int r = 0; r < 4; r++) {
          size_t idx = (size_t)(row + r) * N + col;
          if (EPI == 0) Cb[idx] = f2bf(acc[m][n][r]);
          else          atomicAdd(Cf + idx, acc[m][n][r]);
        }
      }
    }
  }
}

// ------------- flash attention, sliding window + sink, dbuf staging ---------
__global__ __launch_bounds__(256)
void attn_k(const u16* __restrict__ qb, int ldq,
            const u16* __restrict__ kb, int ldk,
            const u16* __restrict__ vbt, u16* __restrict__ ao,
            const float* __restrict__ ct, const float* __restrict__ st)
{
  int q0 = blockIdx.x * 128;
  int h = blockIdx.y;
  int b = blockIdx.z;
  int hk = h >> 2;
  int tid = threadIdx.x;
  int w = tid >> 6, l = tid & 63;
  int l16 = l & 15, lg = l >> 4;

  __shared__ u16 Ks[2][32 * 128];
  __shared__ u16 Vt[2][128 * 32];
  __shared__ u16 Ps[4][32 * 40];
  u16* Pw = Ps[w];

  const float qscale = 0.08838834764831845f;
  bf16x8 qf[2][4];
  #pragma unroll
  for (int m = 0; m < 2; m++) {
    int row = q0 + w * 32 + m * 16 + l16;
    #pragma unroll
    for (int kd = 0; kd < 4; kd++)
      qf[m][kd] = *(const bf16x8*)(qb + (size_t)(b * SEQ + row) * ldq
                                   + h * HDIM + kd * 32 + lg * 8);
    const float* ctp = ct + (size_t)row * 64;
    const float* stp = st + (size_t)row * 64;
    #pragma unroll
    for (int pr = 0; pr < 2; pr++) {
      bf16x8 lo = qf[m][pr], hi = qf[m][pr + 2];
      int dl = pr * 32 + lg * 8;
      #pragma unroll
      for (int j = 0; j < 8; j++) {
        float c = ctp[dl + j], s = stp[dl + j];
        float x1 = (float)lo[j], x2 = (float)hi[j];
        lo[j] = (__bf16)((x1 * c - x2 * s) * qscale);
        hi[j] = (__bf16)((x2 * c + x1 * s) * qscale);
      }
      qf[m][pr] = lo; qf[m][pr + 2] = hi;
    }
  }

  f32x4 oacc[2][8];
  float mrun[2][4], lrun[2][4];
  f32x4 zero = {0.f, 0.f, 0.f, 0.f};
  #pragma unroll
  for (int m = 0; m < 2; m++) {
    #pragma unroll
    for (int nd = 0; nd < 8; nd++) oacc[m][nd] = zero;
    #pragma unroll
    for (int r = 0; r < 4; r++) { mrun[m][r] = -1e9f; lrun[m][r] = 0.f; }
  }

  int kr0 = tid >> 4,        kc0 = (tid & 15) ^ (kr0 & 7);
  int kr1 = (tid + 256) >> 4, kc1 = (tid & 15) ^ (kr1 & 7);
  int vd0, vk0, vd1, vk1;
  swz_rc(tid, vd0, vk0);
  swz_rc(tid + 256, vd1, vk1);
  const u16* kbase = kb + (size_t)(b * SEQ) * ldk + hk * HDIM;
  const u16* vbase = vbt + (size_t)(b * NKV + hk) * HDIM * SEQ;

  int koff[2][4];
  #pragma unroll
  for (int n = 0; n < 2; n++)
    #pragma unroll
    for (int kd = 0; kd < 4; kd++) {
      int key = n * 16 + l16;
      koff[n][kd] = ((key * 128) + kd * 32 + lg * 8) ^ ((key & 7) * 8);
    }
  int voff[8];
  #pragma unroll
  for (int nd = 0; nd < 8; nd++) {
    int d = nd * 16 + l16;
    voff[nd] = (d * 32 + lg * 8) ^ ((d & 7) * 8);
  }

  auto stage = [&](int kt, int bsel) {
    gld16(kbase + (size_t)(kt * 32 + kr0) * ldk + kc0 * 8, Ks[bsel] + tid * 8);
    gld16(kbase + (size_t)(kt * 32 + kr1) * ldk + kc1 * 8, Ks[bsel] + (tid + 256) * 8);
    gld16(vbase + (size_t)vd0 * SEQ + kt * 32 + vk0 * 8, Vt[bsel] + tid * 8);
    gld16(vbase + (size_t)vd1 * SEQ + kt * 32 + vk1 * 8, Vt[bsel] + (tid + 256) * 8);
  };

  int lo = (q0 >= WIN) ? ((q0 - (WIN - 1)) >> 5) : 0;
  int hi = (q0 + 127) >> 5;
  int it0 = (lo > 0 ? lo - 1 : 0);

  stage((it0 < lo) ? 0 : it0, 0);
  int bsel = 0;

  for (int it = it0; it <= hi; ++it) {
    int kt = (it < lo) ? 0 : it;
    if (it < hi) { stage(it + 1, bsel ^ 1); VM(4); }
    else         { VM(0); }
    bar();
    const u16* Ksb = Ks[bsel];
    const u16* Vtb = Vt[bsel];

    f32x4 sacc[2][2];
    sacc[0][0] = zero; sacc[0][1] = zero; sacc[1][0] = zero; sacc[1][1] = zero;
    #pragma unroll
    for (int kd = 0; kd < 4; kd++) {
      bf16x8 kf0 = *(const bf16x8*)(Ksb + koff[0][kd]);
      bf16x8 kf1 = *(const bf16x8*)(Ksb + koff[1][kd]);
      #pragma unroll
      for (int m = 0; m < 2; m++) {
        sacc[m][0] = mfma16(qf[m][kd], kf0, sacc[m][0]);
        sacc[m][1] = mfma16(qf[m][kd], kf1, sacc[m][1]);
      }
    }

    #pragma unroll
    for (int m = 0; m < 2; m++) {
      float sc[4];
      #pragma unroll
      for (int r = 0; r < 4; r++) {
        int i = q0 + w * 32 + m * 16 + lg * 4 + r;
        int j0 = kt * 32 + l16;
        int j1 = j0 + 16;
        float s0 = sacc[m][0][r];
        float s1 = sacc[m][1][r];
        bool ok0 = (j0 <= i) && ((i - j0 < WIN) || (j0 < SINKN));
        bool ok1 = (j1 <= i) && ((i - j1 < WIN) || (j1 < SINKN));
        s0 = ok0 ? s0 : -1e9f;
        s1 = ok1 ? s1 : -1e9f;
        float mx = fmaxf(s0, s1);
        mx = fmaxf(mx, __shfl_xor(mx, 1));
        mx = fmaxf(mx, __shfl_xor(mx, 2));
        mx = fmaxf(mx, __shfl_xor(mx, 4));
        mx = fmaxf(mx, __shfl_xor(mx, 8));
        float mold = mrun[m][r];
        float mnew = fmaxf(mold, mx);
        float scl = __expf(mold - mnew);
        mrun[m][r] = mnew;
        float p0 = __expf(s0 - mnew);
        float p1 = __expf(s1 - mnew);
        int prow = m * 16 + lg * 4 + r;
        Pw[prow * 40 + l16] = f2bf(p0);
        Pw[prow * 40 + 16 + l16] = f2bf(p1);
        float ps = p0 + p1;
        ps += __shfl_xor(ps, 1);
        ps += __shfl_xor(ps, 2);
        ps += __shfl_xor(ps, 4);
        ps += __shfl_xor(ps, 8);
        lrun[m][r] = lrun[m][r] * scl + ps;
        sc[r] = scl;
      }
      #pragma unroll
      for (int nd = 0; nd < 8; nd++) {
        oacc[m][nd][0] *= sc[0];
        oacc[m][nd][1] *= sc[1];
        oacc[m][nd][2] *= sc[2];
        oacc[m][nd][3] *= sc[3];
      }
    }

    bf16x8 pa0 = *(const bf16x8*)(Pw + l16 * 40 + lg * 8);
    bf16x8 pa1 = *(const bf16x8*)(Pw + (16 + l16) * 40 + lg * 8);
    #pragma unroll
    for (int nd = 0; nd < 8; nd++) {
      bf16x8 vf = *(const bf16x8*)(Vtb + voff[nd]);
      oacc[0][nd] = mfma16(pa0, vf, oacc[0][nd]);
      oacc[1][nd] = mfma16(pa1, vf, oacc[1][nd]);
    }
    bar();
    bsel ^= 1;
  }

  #pragma unroll
  for (int m = 0; m < 2; m++)
    #pragma unroll
    for (int r = 0; r < 4; r++) {
      float invl = 1.0f / lrun[m][r];
      int row = q0 + w * 32 + m * 16 + lg * 4 + r;
      #pragma unroll
      for (int nd = 0; nd < 8; nd++) {
        int col = nd * 16 + l16;
        ao[(size_t)(b * SEQ + row) * (NH * HDIM) + h * HDIM + col] =
            f2bf(oacc[m][nd][r] * invl);
      }
    }
}

// ------------------------------- launcher -----------------------------------
extern "C" void kernel_launch(void* const* d_in, const int* in_sizes, int n_in,
                              void* d_out, int out_size, void* d_ws, size_t ws_size,
                              hipStream_t stream)
{
  (void)in_sizes; (void)n_in; (void)out_size;
  const float* x  = (const float*)d_in[0];
  const float* g1 = (const float*)d_in[1];
  const float* g2 = (const float*)d_in[2];
  const float* wq = (const float*)d_in[3];
  const float* wk = (const float*)d_in[4];
  const float* wv = (const float*)d_in[5];
  const float* wo = (const float*)d_in[6];
  const float* wg = (const float*)d_in[7];
  const float* wu = (const float*)d_in[8];
  const float* wd = (const float*)d_in[9];
  float* out = (float*)d_out;

  char* ws = (char*)d_ws;
  size_t off = 0;
  auto alloc = [&](size_t bytes) {
    char* p = ws + off;
    off += (bytes + 255) & ~(size_t)255;
    return p;
  };
  const int NQKV = 3072;   // q 0..2047 | k 2048..2559 | v 2560..3071
  u16* wqkv_t = (u16*)alloc((size_t)NQKV * DM * 2);
  u16* wo_t   = (u16*)alloc((size_t)DM * DM * 2);
  u16* wg_t   = (u16*)alloc((size_t)HID * DM * 2);
  u16* wu_t   = (u16*)alloc((size_t)HID * DM * 2);
  u16* wd_t   = (u16*)alloc((size_t)DM * HID * 2);
  u16* hb     = (u16*)alloc((size_t)TOK * DM * 2);
  // gu (67.1 MB) aliases qkvb+vbt+aob (dead by the time gateup runs) + tail
  char* span0 = ws + off;
  u16* qkvb   = (u16*)alloc((size_t)TOK * NQKV * 2);
  u16* vbt    = (u16*)alloc((size_t)TOK * NKV * HDIM * 2);
  u16* aob    = (u16*)alloc((size_t)TOK * NH * HDIM * 2);
  size_t span_used = (size_t)(ws + off - span0);
  size_t gu_need = (size_t)TOK * HID * 2;
  if (gu_need > span_used) alloc(gu_need - span_used);
  u16* gu = (u16*)span0;
  float* ct  = (float*)alloc((size_t)SEQ * 64 * 4);
  float* st  = (float*)alloc((size_t)SEQ * 64 * 4);
  if (off > ws_size) return;

  dim3 blk(256);
  dim3 blk512(512);

  // setup: weight transposes + rope table + rmsnorm1, one dispatch
  setup_all<<<dim3(64000), blk, 0, stream>>>(wq, wk, wv, wo, wg, wu, wd,
                                             wqkv_t, wo_t, wg_t, wu_t, wd_t,
                                             ct, st, x, g1, hb);

  // fused QKV projection: [4096][3072] (192 blocks)
  gemm256<0, 0, 0><<<dim3((NQKV / 256) * (TOK / 256)), blk512, 0, stream>>>(
      hb, wqkv_t, nullptr, qkvb, nullptr, DM, DM / 64, NQKV, NQKV / 256);

  // K rope + V transpose, one dispatch
  kv_post<<<dim3(6144), blk, 0, stream>>>(qkvb, ct, st, vbt);

  attn_k<<<dim3(SEQ / 128, NH, 2), blk, 0, stream>>>(qkvb, NQKV, qkvb + DM, NQKV, vbt, aob, ct, st);

  // wo: out = x + aob @ wo^T (no atomics)
  gemmp<1><<<dim3((DM / 256) * (TOK / 128)), blk512, 0, stream>>>(
      aob, wo_t, nullptr, out, x, TOK, DM, DM, DM / 256);
  rmsnorm_k<<<TOK, blk, 0, stream>>>(out, g2, hb);

  // fused gate+up with silu epilogue (1024 blocks)
  gemm256<0, 1, 0><<<dim3((HID / 128) * (TOK / 256)), blk512, 0, stream>>>(
      hb, wg_t, wu_t, gu, nullptr, DM, DM / 64, HID, HID / 128);

  // down-proj: split-K=2, atomicAdd into out (256 blocks)
  gemm256<4, 0, 1><<<dim3(2 * (DM / 256) * (TOK / 256)), blk512, 0, stream>>>(
      gu, wd_t, nullptr, nullptr, out, HID, HID / 128, DM, DM / 256);
}